// Round 7
// baseline (964.420 us; speedup 1.0000x reference)
//
#include <hip/hip_runtime.h>
#include <math.h>

#define BB 8
#define TT 512
#define HH 1024
#define NAc 1024
#define NPc 512
#define NWc 16
#define WDc 20
#define NCLSc 66
#define KARG 30
#define KPRED 15
#define NEGV (-1e20f)

typedef __bf16 bf16x8 __attribute__((ext_vector_type(8)));
typedef float  f32x4  __attribute__((ext_vector_type(4)));

#define LDS_U32(p) ((__attribute__((address_space(3))) unsigned int*)(p))
#define GLB_U32(p) ((const __attribute__((address_space(1))) unsigned int*)(p))

// ---------------- workspace layout (float offsets) ----------------
// Region A: five token-projection buffers [4096x1024] f32, CONSECUTIVE (k_mgemm indexes part*4096*1024).
#define OFF_PAS   0
#define OFF_PAE   (OFF_PAS  + BB*TT*HH)
#define OFF_PATT  (OFF_PAE  + BB*TT*HH)
#define OFF_PPS   (OFF_PATT + BB*TT*HH)
#define OFF_PPE   (OFF_PPS  + BB*TT*HH)
#define OFF_END_A (OFF_PPE  + BB*TT*HH)
// Aliased region (live AFTER prune scores are consumed) — overlaps Region A.
#define OFF_AEMB  OFF_PAS
#define OFF_PEMB  OFF_PAE
#define OFF_CPA   OFF_PATT
#define OFF_CPP   OFF_PPS
#define OFF_APROJ OFF_PPE
#define OFF_PPROJ (OFF_PPE + BB*KARG*HH)
// Persistent small region.
#define OFF_LOG   OFF_END_A
#define OFF_WT    (OFF_LOG  + BB*TT)
#define OFF_AIDX  (OFF_WT   + NWc*HH)
#define OFF_PIDX  (OFF_AIDX + BB*KARG)
#define OFF_ASC   (OFF_PIDX + BB*KPRED)
#define OFF_PSC   (OFF_ASC  + BB*KARG)
// Split bf16 slabs (ushort): X hi/mid/lo [4096x1024] + Wt hi/mid/lo [5 parts][1024N][1024K] transposed.
#define OFF_SPLIT (OFF_PSC + BB*KPRED)
#define XSLAB_U   (4096*1024)          // ushorts per X slab
#define WSLAB_U   (5*1024*1024)        // ushorts per W slab set (5 parts)

// ---------------- d_out layout (float offsets) ----------------
#define O_SRL 0
#define O_TPS (O_SRL + BB*KPRED*KARG*NCLSc)
#define O_TAS (O_TPS + BB*KPRED*2)
#define O_TPM (O_TAS + BB*KARG*2)
#define O_TAM (O_TPM + BB*KPRED)
#define O_PFS (O_TAM + BB*KARG)
#define O_AFS (O_PFS + BB*NPc)

__device__ inline float4 f4_add(const float4&a,const float4&b){return make_float4(a.x+b.x,a.y+b.y,a.z+b.z,a.w+b.w);}
__device__ inline float4 f4_fma(float c,const float4&v,const float4&a){return make_float4(fmaf(c,v.x,a.x),fmaf(c,v.y,a.y),fmaf(c,v.z,a.z),fmaf(c,v.w,a.w));}
__device__ inline float4 f4_scale(const float4&v,float c){return make_float4(v.x*c,v.y*c,v.z*c,v.w*c);}
__device__ inline float4 f4_relu(const float4&v){return make_float4(fmaxf(v.x,0.f),fmaxf(v.y,0.f),fmaxf(v.z,0.f),fmaxf(v.w,0.f));}

// bf16 round-to-nearest-even from fp32 bits
__device__ inline unsigned short bf16r(float f) {
  unsigned int u = __float_as_uint(f);
  u = (u + 0x7FFFu + ((u >> 16) & 1u)) >> 16;
  return (unsigned short)u;
}
__device__ inline float bf2f(unsigned short h) { return __uint_as_float(((unsigned int)h) << 16); }

__device__ inline f32x4 mfma16(bf16x8 a, bf16x8 b, f32x4 c) {
  return __builtin_amdgcn_mfma_f32_16x16x32_bf16(a, b, c, 0, 0, 0);
}

// ---------------- K1: global attention logits ----------------
__global__ __launch_bounds__(256) void k_logits(const float* __restrict__ f, const float* __restrict__ Watt,
    const float* __restrict__ batt, float* __restrict__ lg) {
  const int lane = threadIdx.x & 63, wv = threadIdx.x >> 6;
  const int r = blockIdx.x*4 + wv;
  const float4* x = (const float4*)&f[(size_t)r*HH];
  const float4* wt = (const float4*)Watt;
  float s = 0.f;
  #pragma unroll
  for (int i=0;i<4;++i) {
    const float4 v = x[lane + i*64];
    const float4 w = wt[lane + i*64];
    s += v.x*w.x + v.y*w.y + v.z*w.z + v.w*w.w;
  }
  for (int o=32;o>0;o>>=1) s += __shfl_down(s,o,64);
  if (lane==0) lg[r] = s + batt[0];
}

// ---------------- width table: WT[w] = W_width[w] @ Wa1[2048:2068] (fp32 exact) ----------------
__global__ __launch_bounds__(256) void k_wtab(const float* __restrict__ Wwidth, const float* __restrict__ src,
    float* __restrict__ WT) {
  const int w = blockIdx.x; const int j = threadIdx.x*4;
  float4 acc = make_float4(0,0,0,0);
  for (int d=0; d<WDc; ++d) {
    const float c = Wwidth[w*WDc+d];
    const float4 v = *(const float4*)&src[d*HH + j];
    acc = f4_fma(c, v, acc);
  }
  *(float4*)&WT[w*HH + j] = acc;
}

// ---------------- split X into 3 bf16 slabs (exact decomposition) ----------------
__global__ __launch_bounds__(256) void k_splitX(const float* __restrict__ f,
    unsigned short* __restrict__ X0, unsigned short* __restrict__ X1, unsigned short* __restrict__ X2) {
  const size_t i = ((size_t)blockIdx.x*256 + threadIdx.x) * 4;
  const float4 v = *(const float4*)&f[i];
  float a[4] = {v.x, v.y, v.z, v.w};
  unsigned short r0[4], r1[4], r2[4];
  #pragma unroll
  for (int q=0;q<4;++q) {
    r0[q] = bf16r(a[q]);            float rem1 = a[q] - bf2f(r0[q]);
    r1[q] = bf16r(rem1);            float rem2 = rem1 - bf2f(r1[q]);
    r2[q] = bf16r(rem2);
  }
  *(ushort4*)&X0[i] = make_ushort4(r0[0],r0[1],r0[2],r0[3]);
  *(ushort4*)&X1[i] = make_ushort4(r1[0],r1[1],r1[2],r1[3]);
  *(ushort4*)&X2[i] = make_ushort4(r2[0],r2[1],r2[2],r2[3]);
}

// ---------------- split + transpose W parts: Wt[s][part][n][k] bf16 ----------------
__global__ __launch_bounds__(256) void k_splitW(const float* __restrict__ Wa1, const float* __restrict__ Wp1,
    unsigned short* __restrict__ W0, unsigned short* __restrict__ W1, unsigned short* __restrict__ W2) {
  const int part = blockIdx.z;
  const float* srcs[5] = {Wa1, Wa1 + 1024*1024, Wa1 + 2068*1024, Wp1, Wp1 + 1024*1024};
  const float* __restrict__ src = srcs[part];
  const size_t po = (size_t)part * 1024 * 1024;
  const int k0 = blockIdx.x * 32, n0 = blockIdx.y * 32;
  __shared__ float tile[32][33];
  const int c = threadIdx.x & 31, r0 = threadIdx.x >> 5;   // r0: 0..7
  #pragma unroll
  for (int q=0;q<4;++q) {
    const int row = r0 + 8*q;                               // k-local
    tile[row][c] = src[(size_t)(k0+row)*1024 + n0 + c];
  }
  __syncthreads();
  #pragma unroll
  for (int q=0;q<4;++q) {
    const int nl = r0 + 8*q;                                // n-local
    const float v = tile[c][nl];                            // transposed read
    const unsigned short h0 = bf16r(v);   const float rem1 = v - bf2f(h0);
    const unsigned short h1 = bf16r(rem1); const float rem2 = rem1 - bf2f(h1);
    const unsigned short h2 = bf16r(rem2);
    const size_t oi = po + (size_t)(n0+nl)*1024 + k0 + c;
    W0[oi] = h0; W1[oi] = h1; W2[oi] = h2;
  }
}

// ---------------- K2: 6-term split GEMM as ONE bf16 GEMM with K=6144 ----------------
// Terms t=0..5: (Xa,Wb) = (0,0),(0,1),(1,0),(1,1),(0,2),(2,0).  Sum of all terms
// reproduces fp32 X@W to ~2^-24 relative (dropped terms are lo*mid and lo*lo).
// m97 structure: 128^2 tile, BK=64, single-buffer LDS, global_load_lds(16B), 16x16x32 MFMA.
// Term loop is #pragma unroll so XA[t]/WB[t] constant-fold (no scratch, rule #20).
__global__ __launch_bounds__(256) void k_mgemm(
    const unsigned short* __restrict__ X0, const unsigned short* __restrict__ X1, const unsigned short* __restrict__ X2,
    const unsigned short* __restrict__ W0, const unsigned short* __restrict__ W1, const unsigned short* __restrict__ W2,
    float* __restrict__ proj) {
  const int part = blockIdx.z;
  const int rb = blockIdx.x * 128, cb = blockIdx.y * 128;
  float* __restrict__ C = proj + (size_t)part * (4096*1024);
  const size_t po = (size_t)part * 1024 * 1024;

  __shared__ unsigned short As[128][64];   // 16 KB
  __shared__ unsigned short Bs[128][64];   // 16 KB

  const int tid = threadIdx.x;
  const int lane = tid & 63, wave = tid >> 6;
  const int wr = wave >> 1, wc = wave & 1;          // 2x2 waves, 64x64 each
  const int r16 = lane & 15, g8 = (lane >> 4) * 8;

  // staging geometry: wave w, instr i -> 8 rows [w*32+i*8 .. +8);
  // lane l covers (row += l>>3, 16B seg (l&7)) — matches linear LDS dest (base + lane*16B).
  const int srow = (lane >> 3);        // 0..7
  const int sseg = (lane & 7) * 8;     // bf16 offset within row

  f32x4 acc[4][4];
  #pragma unroll
  for (int i=0;i<4;++i)
    #pragma unroll
    for (int j=0;j<4;++j) acc[i][j] = (f32x4){0.f,0.f,0.f,0.f};

  const unsigned short* const XA[6] = {X0, X0, X1, X1, X0, X2};
  const unsigned short* const WB[6] = {W0+po, W1+po, W0+po, W1+po, W2+po, W0+po};

  #pragma unroll
  for (int t = 0; t < 6; ++t) {                 // unrolled: ap/bp are compile-time selections
    const unsigned short* __restrict__ ap = XA[t];
    const unsigned short* __restrict__ bp = WB[t];
    for (int kc = 0; kc < 16; ++kc) {           // 16 K-chunks of 64 per term
      const int kbase = kc * 64;
      #pragma unroll
      for (int i = 0; i < 4; ++i) {
        const int rl = wave*32 + i*8;
        __builtin_amdgcn_global_load_lds(
            GLB_U32(ap + (size_t)(rb + rl + srow)*1024 + kbase + sseg),
            LDS_U32(&As[rl][0]), 16, 0, 0);
        __builtin_amdgcn_global_load_lds(
            GLB_U32(bp + (size_t)(cb + rl + srow)*1024 + kbase + sseg),
            LDS_U32(&Bs[rl][0]), 16, 0, 0);
      }
      __syncthreads();   // compiler emits vmcnt(0) drain before barrier

      #pragma unroll
      for (int ks = 0; ks < 2; ++ks) {
        bf16x8 a[4], b[4];
        #pragma unroll
        for (int mf=0; mf<4; ++mf)
          a[mf] = *reinterpret_cast<const bf16x8*>(&As[wr*64 + mf*16 + r16][ks*32 + g8]);
        #pragma unroll
        for (int nf=0; nf<4; ++nf)
          b[nf] = *reinterpret_cast<const bf16x8*>(&Bs[wc*64 + nf*16 + r16][ks*32 + g8]);
        #pragma unroll
        for (int mf=0; mf<4; ++mf)
          #pragma unroll
          for (int nf=0; nf<4; ++nf)
            acc[mf][nf] = mfma16(a[mf], b[nf], acc[mf][nf]);
      }
      __syncthreads();   // protect LDS before next stage
    }
  }

  // C/D layout (m89-verified): col = lane&15, row = (lane>>4)*4 + reg
  const int colb = cb + wc*64 + r16;
  const int rowb = rb + wr*64 + (lane >> 4) * 4;
  #pragma unroll
  for (int mf=0; mf<4; ++mf)
    #pragma unroll
    for (int nf=0; nf<4; ++nf)
      #pragma unroll
      for (int r=0; r<4; ++r)
        C[(size_t)(rowb + mf*16 + r) * 1024 + colb + nf*16] = acc[mf][nf][r];
}

// ---------------- attention weight helper ----------------
__device__ inline void att_weights(const float* __restrict__ logits, int b, int sr, int er,
                                   float aw[16], int idxs[16]) {
  const int wdt = er - sr;
  float mx = -1e30f;
  #pragma unroll
  for (int w=0; w<16; ++w) {
    const bool valid = (w <= wdt) && (er - w >= 0);
    idxs[w] = max(er - w, 0);
    aw[w] = valid ? logits[b*TT + idxs[w]] : -1e30f;
    mx = fmaxf(mx, aw[w]);
  }
  float ssum = 0.f;
  #pragma unroll
  for (int w=0; w<16; ++w) { aw[w] = expf(aw[w]-mx); ssum += aw[w]; }
  const float inv = 1.f/ssum;
  #pragma unroll
  for (int w=0; w<16; ++w) {
    const bool valid = (w <= wdt) && (er - w >= 0);
    aw[w] = valid ? aw[w]*inv : 0.f;
  }
}

// ---------------- K3: arg prune scores ----------------
__global__ __launch_bounds__(256) void k_argscore(const int* __restrict__ cand,
    const float* __restrict__ logits, const float* __restrict__ Pas, const float* __restrict__ Pae,
    const float* __restrict__ Patt, const float* __restrict__ WT,
    const float* __restrict__ ba1, const float* __restrict__ Wa2, const float* __restrict__ ba2,
    float* __restrict__ osc) {
  const int g = blockIdx.x;       // b*NA + n
  const int b = g >> 10;
  const int t = threadIdx.x;
  const int sr = cand[g*2], er = cand[g*2+1];
  if (er <= 0) { if (t==0) osc[g] = NEGV; return; }
  const int s = sr, e = er;
  const int wc = min(max(e - s, 0), NWc-1);
  float aw[16]; int idxs[16];
  att_weights(logits, b, sr, er, aw, idxs);
  float4 h = ((const float4*)&Pas[(size_t)(b*TT+s)*HH])[t];
  h = f4_add(h, ((const float4*)&Pae[(size_t)(b*TT+e)*HH])[t]);
  h = f4_add(h, ((const float4*)&WT[(size_t)wc*HH])[t]);
  #pragma unroll
  for (int w=0; w<16; ++w) if (aw[w] != 0.f) {
    const float4 v = ((const float4*)&Patt[(size_t)(b*TT+idxs[w])*HH])[t];
    h = f4_fma(aw[w], v, h);
  }
  h = f4_add(h, ((const float4*)ba1)[t]);
  h = f4_relu(h);
  const float4 w2 = ((const float4*)Wa2)[t];
  float part = h.x*w2.x + h.y*w2.y + h.z*w2.z + h.w*w2.w;
  for (int o=32;o>0;o>>=1) part += __shfl_down(part,o,64);
  __shared__ float red[4];
  const int lane = t & 63, wvi = t >> 6;
  if (lane==0) red[wvi] = part;
  __syncthreads();
  if (t==0) osc[g] = red[0]+red[1]+red[2]+red[3] + ba2[0];
}

// ---------------- K4: pred prune scores ----------------
__global__ __launch_bounds__(256) void k_predscore(const int* __restrict__ cand,
    const float* __restrict__ Pps, const float* __restrict__ Ppe,
    const float* __restrict__ bp1, const float* __restrict__ Wp2, const float* __restrict__ bp2,
    float* __restrict__ osc) {
  const int g = blockIdx.x;       // b*NP + n
  const int b = g >> 9;
  const int t = threadIdx.x;
  const int sr = cand[g*2], er = cand[g*2+1];
  if (er <= 0) { if (t==0) osc[g] = NEGV; return; }
  float4 h = ((const float4*)&Pps[(size_t)(b*TT+sr)*HH])[t];
  h = f4_add(h, ((const float4*)&Ppe[(size_t)(b*TT+er)*HH])[t]);
  h = f4_add(h, ((const float4*)bp1)[t]);
  h = f4_relu(h);
  const float4 w2 = ((const float4*)Wp2)[t];
  float part = h.x*w2.x + h.y*w2.y + h.z*w2.z + h.w*w2.w;
  for (int o=32;o>0;o>>=1) part += __shfl_down(part,o,64);
  __shared__ float red[4];
  const int lane = t & 63, wvi = t >> 6;
  if (lane==0) red[wvi] = part;
  __syncthreads();
  if (t==0) osc[g] = red[0]+red[1]+red[2]+red[3] + bp2[0];
}

// ---------------- K5: top-k (lax.top_k semantics) + outputs ----------------
__global__ __launch_bounds__(256) void k_topk(const float* __restrict__ fullsc, const int* __restrict__ cand,
    int N, int K, float frac, float* __restrict__ o_spans, float* __restrict__ o_mask,
    float* __restrict__ o_tsc, int* __restrict__ o_idx) {
  const int b = blockIdx.x;
  const int t = threadIdx.x;
  __shared__ float sv[1024];
  __shared__ int sel[32];
  __shared__ float bv[4]; __shared__ int bi[4];
  __shared__ int mcnt; __shared__ int snk;
  const float* sc = fullsc + (size_t)b*N;
  const int* cd = cand + (size_t)b*N*2;
  if (t==0) mcnt = 0;
  __syncthreads();
  int cnt = 0;
  for (int i=t;i<N;i+=256){ sv[i]=sc[i]; if (cd[i*2+1] > 0) cnt++; }
  atomicAdd(&mcnt, cnt);
  __syncthreads();
  const int lane = t & 63, wvi = t >> 6;
  for (int k=0;k<K;++k) {
    float best = -INFINITY; int bidx = 1<<30;
    for (int i=t;i<N;i+=256){ const float v=sv[i]; if (v>best){best=v;bidx=i;} }
    for (int o=32;o>0;o>>=1){
      const float v2 = __shfl_down(best,o,64); const int i2 = __shfl_down(bidx,o,64);
      if (v2>best || (v2==best && i2<bidx)) {best=v2;bidx=i2;}
    }
    if (lane==0){bv[wvi]=best;bi[wvi]=bidx;}
    __syncthreads();
    if (t==0){
      float bb=bv[0]; int ii=bi[0];
      for (int w=1;w<4;++w){ if (bv[w]>bb || (bv[w]==bb && bi[w]<ii)){bb=bv[w];ii=bi[w];} }
      sel[k]=ii; sv[ii] = -INFINITY;
    }
    __syncthreads();
  }
  if (t==0) {
    int nk = (int)((float)mcnt * frac); if (nk > K) nk = K;
    snk = nk;
    int fill = 0;
    for (int k=0;k<K;++k) fill = max(fill, sel[k]);
    for (int k=nk;k<K;++k) sel[k] = fill;
    for (int k=1;k<K;++k){ int v=sel[k]; int j=k-1; while(j>=0 && sel[j]>v){sel[j+1]=sel[j];--j;} sel[j+1]=v; }
  }
  __syncthreads();
  if (t < K) {
    const int id = sel[t];
    const int s0 = cd[id*2], e0 = cd[id*2+1];
    o_spans[(b*K+t)*2]   = (float)s0;
    o_spans[(b*K+t)*2+1] = (float)e0;
    o_mask[b*K+t] = (t < snk && e0 > 0) ? 1.f : 0.f;
    o_tsc[b*K+t] = sc[id];
    o_idx[b*K+t] = id;
  }
}

// ---------------- K7a/b: build compact embedding rows for kept spans ----------------
__global__ __launch_bounds__(256) void k_build_pemb(const float* __restrict__ f, const int* __restrict__ cand,
    const int* __restrict__ tidx, float* __restrict__ Pemb) {
  const int r = blockIdx.x;           // 0..119
  const int b = r / KPRED;
  const int id = tidx[r];
  int s = cand[(b*NPc+id)*2], e = cand[(b*NPc+id)*2+1];
  const float mf = (e > 0) ? 1.f : 0.f;
  if (e <= 0) { s = 0; e = 0; }
  const int t = threadIdx.x;
  const float4 fs = ((const float4*)&f[(size_t)(b*TT+s)*HH])[t];
  const float4 fe = ((const float4*)&f[(size_t)(b*TT+e)*HH])[t];
  float4* o = (float4*)&Pemb[(size_t)r*2048];
  o[t]     = f4_scale(fs, mf);
  o[256+t] = f4_scale(fe, mf);
}

__global__ __launch_bounds__(256) void k_build_aemb(const float* __restrict__ f, const int* __restrict__ cand,
    const int* __restrict__ tidx, const float* __restrict__ logits, const float* __restrict__ Wwidth,
    float* __restrict__ Aemb) {
  const int r = blockIdx.x;           // 0..239
  const int b = r / KARG;
  const int id = tidx[r];
  const int sr = cand[(b*NAc+id)*2], er = cand[(b*NAc+id)*2+1];
  const float mf = (er > 0) ? 1.f : 0.f;
  const int s = (er > 0) ? sr : 0, e = (er > 0) ? er : 0;
  const int wc = min(max(e - s, 0), NWc-1);
  float aw[16]; int idxs[16];
  att_weights(logits, b, sr, er, aw, idxs);
  const int t = threadIdx.x;
  float* rowp = &Aemb[(size_t)r*3092];
  const float4 fs  = ((const float4*)&f[(size_t)(b*TT+s)*HH])[t];
  const float4 fe4 = ((const float4*)&f[(size_t)(b*TT+e)*HH])[t];
  ((float4*)rowp)[t]        = f4_scale(fs, mf);
  ((float4*)(rowp+1024))[t] = f4_scale(fe4, mf);
  if (t < WDc) rowp[2048+t] = Wwidth[wc*WDc+t]*mf;
  float4 acc = make_float4(0,0,0,0);
  #pragma unroll
  for (int w=0; w<16; ++w) if (aw[w] != 0.f) {
    const float4 fv = ((const float4*)&f[(size_t)(b*TT+idxs[w])*HH])[t];
    acc = f4_fma(aw[w], fv, acc);
  }
  ((float4*)(rowp+2068))[t] = f4_scale(acc, mf);
}

// ---------------- K7c: small-M GEMM with k-split: Cp[kz] = A[b-rows] @ W ----------------
template<int MT>
__global__ __launch_bounds__(256) void k_sgemm(const float* __restrict__ A, int lda, int K,
                                               const float* __restrict__ W, float* __restrict__ Cp) {
  const int ct = blockIdx.x;          // 8 col tiles of 128
  const int b  = blockIdx.y;          // 8 batches
  const int kz = blockIdx.z;          // 4 k splits
  const int Mtotal = 8*MT;
  const int cbase = ct*128;
  const int rbase = b*MT;
  const int klen = K/4;
  const int kbeg = kz*klen, kend = kbeg + klen;
  __shared__ float As[MT][64];
  const int tid = threadIdx.x;
  const int lane = tid & 63, wv = tid >> 6;
  const int ks = lane & 7;
  const int cg = wv*8 + (lane >> 3);  // 0..31
  const int col = cbase + cg*4;
  float acc[MT][4];
  #pragma unroll
  for (int m=0;m<MT;++m){acc[m][0]=0.f;acc[m][1]=0.f;acc[m][2]=0.f;acc[m][3]=0.f;}
  for (int k0 = kbeg; k0 < kend; k0 += 64) {
    const int kc = min(64, kend - k0);
    for (int i = tid; i < MT*64; i += 256) {
      const int m = i >> 6, kk = i & 63;
      As[m][kk] = (kk < kc) ? A[(size_t)(rbase+m)*lda + k0 + kk] : 0.f;
    }
    __syncthreads();
    const int kmax = min(8, kc - ks*8);
    for (int i = 0; i < kmax; ++i) {
      const int kk = ks*8 + i;
      const float4 wv4 = *(const float4*)&W[(size_t)(k0+kk)*1024 + col];
      #pragma unroll
      for (int m=0;m<MT;++m) {
        const float av = As[m][kk];
        acc[m][0] = fmaf(av, wv4.x, acc[m][0]);
        acc[m][1] = fmaf(av, wv4.y, acc[m][1]);
        acc[m][2] = fmaf(av, wv4.z, acc[m][2]);
        acc[m][3] = fmaf(av, wv4.w, acc[m][3]);
      }
    }
    __syncthreads();
  }
  #pragma unroll
  for (int m=0;m<MT;++m) {
    #pragma unroll
    for (int j=0;j<4;++j) {
      float v = acc[m][j];
      v += __shfl_xor(v, 1, 64);
      v += __shfl_xor(v, 2, 64);
      v += __shfl_xor(v, 4, 64);
      acc[m][j] = v;
    }
  }
  if (ks == 0) {
    #pragma unroll
    for (int m=0;m<MT;++m) {
      const float4 v = make_float4(acc[m][0],acc[m][1],acc[m][2],acc[m][3]);
      *(float4*)&Cp[((size_t)kz*Mtotal + rbase + m)*1024 + col] = v;
    }
  }
}

__global__ void k_reduce4(const float* __restrict__ Cp, float* __restrict__ Co, int n) {
  const int i = blockIdx.x*256 + threadIdx.x;
  if (i < n) Co[i] = Cp[i] + Cp[(size_t)n+i] + Cp[2*(size_t)n+i] + Cp[3*(size_t)n+i];
}

// ---------------- K8: pairwise 65-class scorer ----------------
__global__ __launch_bounds__(256) void k_final(const float* __restrict__ pproj, const float* __restrict__ aproj,
    const float* __restrict__ bs1, const float* __restrict__ Ws2, const float* __restrict__ bs2,
    const float* __restrict__ tasc, const float* __restrict__ tpsc, float* __restrict__ srl) {
  const int g = blockIdx.x;           // b*450 + p*30 + a
  const int b = g / (KPRED*KARG);
  const int rem = g % (KPRED*KARG);
  const int p = rem / KARG, a = rem % KARG;
  const int t = threadIdx.x;
  __shared__ float h[1024];
  __shared__ float part[4][64];
  __shared__ float r64[4];
  {
    const float4 pv = ((const float4*)&pproj[(size_t)(b*KPRED+p)*HH])[t];
    const float4 av = ((const float4*)&aproj[(size_t)(b*KARG+a)*HH])[t];
    const float4 bv = ((const float4*)bs1)[t];
    float4 v;
    v.x = fmaxf(pv.x+av.x+bv.x, 0.f);
    v.y = fmaxf(pv.y+av.y+bv.y, 0.f);
    v.z = fmaxf(pv.z+av.z+bv.z, 0.f);
    v.w = fmaxf(pv.w+av.w+bv.w, 0.f);
    ((float4*)h)[t] = v;
  }
  __syncthreads();
  const int j = t & 63, sl = t >> 6;
  float accj = 0.f, acc64 = 0.f;
  const int kb = sl*256;
  for (int kk = kb; kk < kb+256; ++kk) {
    const float hv = h[kk];
    accj = fmaf(hv, Ws2[(size_t)kk*65 + j], accj);
    if (j == 0) acc64 = fmaf(hv, Ws2[(size_t)kk*65 + 64], acc64);
  }
  part[sl][j] = accj;
  if (j == 0) r64[sl] = acc64;
  __syncthreads();
  const float base = tasc[b*KARG+a] + tpsc[b*KPRED+p];
  float* o = &srl[(size_t)g*NCLSc];
  if (t < 64) {
    o[1+t] = part[0][t]+part[1][t]+part[2][t]+part[3][t] + bs2[t] + base;
  } else if (t == 64) {
    o[0] = 0.f;
    o[65] = r64[0]+r64[1]+r64[2]+r64[3] + bs2[64] + base;
  }
}

// ---------------- launch ----------------
extern "C" void kernel_launch(void* const* d_in, const int* in_sizes, int n_in,
                              void* d_out, int out_size, void* d_ws, size_t ws_size,
                              hipStream_t stream) {
  const float* features = (const float*)d_in[0];
  const int*   argc_    = (const int*)d_in[1];
  const int*   predc    = (const int*)d_in[2];
  const float* Wwidth   = (const float*)d_in[3];
  const float* Watt     = (const float*)d_in[4];
  const float* batt     = (const float*)d_in[5];
  const float* Wa1      = (const float*)d_in[6];
  const float* ba1      = (const float*)d_in[7];
  const float* Wa2      = (const float*)d_in[8];
  const float* ba2      = (const float*)d_in[9];
  const float* Wp1      = (const float*)d_in[10];
  const float* bp1      = (const float*)d_in[11];
  const float* Wp2      = (const float*)d_in[12];
  const float* bp2      = (const float*)d_in[13];
  const float* Ws1      = (const float*)d_in[14];
  const float* bs1      = (const float*)d_in[15];
  const float* Ws2      = (const float*)d_in[16];
  const float* bs2      = (const float*)d_in[17];
  float* ws  = (float*)d_ws;
  float* out = (float*)d_out;

  unsigned short* X0 = (unsigned short*)(ws + OFF_SPLIT);
  unsigned short* X1 = X0 + XSLAB_U;
  unsigned short* X2 = X1 + XSLAB_U;
  unsigned short* W0 = X2 + XSLAB_U;
  unsigned short* W1 = W0 + WSLAB_U;
  unsigned short* W2 = W1 + WSLAB_U;

  // 1. logits
  k_logits<<<dim3(BB*TT/4), 256, 0, stream>>>(features, Watt, batt, ws + OFF_LOG);
  // 2. width table (fp32 exact)
  k_wtab<<<dim3(NWc), 256, 0, stream>>>(Wwidth, Wa1 + 2048*1024, ws + OFF_WT);
  // 3. split X and the 5 W parts into 3-way bf16 (W transposed to [n][k])
  k_splitX<<<dim3(4096), 256, 0, stream>>>(features, X0, X1, X2);
  k_splitW<<<dim3(32, 32, 5), 256, 0, stream>>>(Wa1, Wp1, W0, W1, W2);
  // 4. MFMA GEMM, K=6144 slab-pair schedule (fp32-class accuracy, m97 structure)
  k_mgemm<<<dim3(32, 8, 5), 256, 0, stream>>>(X0, X1, X2, W0, W1, W2, ws + OFF_PAS);
  // 5. prune scores (consume projections; Region A dead afterwards)
  k_argscore<<<dim3(BB*NAc), 256, 0, stream>>>(argc_, ws + OFF_LOG, ws + OFF_PAS, ws + OFF_PAE,
      ws + OFF_PATT, ws + OFF_WT, ba1, Wa2, ba2, out + O_AFS);
  k_predscore<<<dim3(BB*NPc), 256, 0, stream>>>(predc, ws + OFF_PPS, ws + OFF_PPE,
      bp1, Wp2, bp2, out + O_PFS);
  // 6. top-k + span/mask outputs
  k_topk<<<dim3(BB), 256, 0, stream>>>(out + O_AFS, argc_, NAc, KARG, 0.8f,
      out + O_TAS, out + O_TAM, ws + OFF_ASC, (int*)(ws + OFF_AIDX));
  k_topk<<<dim3(BB), 256, 0, stream>>>(out + O_PFS, predc, NPc, KPRED, 0.4f,
      out + O_TPS, out + O_TPM, ws + OFF_PSC, (int*)(ws + OFF_PIDX));
  // 7. build compact embeddings for kept spans (aliased over Region A — stream-ordered, safe)
  k_build_aemb<<<dim3(BB*KARG), 256, 0, stream>>>(features, argc_, (const int*)(ws + OFF_AIDX),
      ws + OFF_LOG, Wwidth, ws + OFF_AEMB);
  k_build_pemb<<<dim3(BB*KPRED), 256, 0, stream>>>(features, predc, (const int*)(ws + OFF_PIDX),
      ws + OFF_PEMB);
  // 8. pairwise projections (fp32 small GEMMs, k-split x4) + reduce
  k_sgemm<KARG><<<dim3(8, 8, 4), 256, 0, stream>>>(ws + OFF_AEMB, 3092, 3092, Ws1 + (size_t)2048*1024, ws + OFF_CPA);
  k_sgemm<KPRED><<<dim3(8, 8, 4), 256, 0, stream>>>(ws + OFF_PEMB, 2048, 2048, Ws1, ws + OFF_CPP);
  k_reduce4<<<dim3((BB*KARG*HH + 255)/256), 256, 0, stream>>>(ws + OFF_CPA, ws + OFF_APROJ, BB*KARG*HH);
  k_reduce4<<<dim3((BB*KPRED*HH + 255)/256), 256, 0, stream>>>(ws + OFF_CPP, ws + OFF_PPROJ, BB*KPRED*HH);
  // 9. pairwise scorer -> srl_scores
  k_final<<<dim3(BB*KPRED*KARG), 256, 0, stream>>>(ws + OFF_PPROJ, ws + OFF_APROJ,
      bs1, Ws2, bs2, ws + OFF_ASC, ws + OFF_PSC, out + O_SRL);
}

// Round 10
// 892.927 us; speedup vs baseline: 1.0801x; 1.0801x over previous
//
#include <hip/hip_runtime.h>
#include <math.h>

#define BB 8
#define TT 512
#define HH 1024
#define NAc 1024
#define NPc 512
#define NWc 16
#define WDc 20
#define NCLSc 66
#define KARG 30
#define KPRED 15
#define NEGV (-1e20f)

typedef __bf16 bf16x8 __attribute__((ext_vector_type(8)));
typedef float  f32x4  __attribute__((ext_vector_type(4)));

#define LDS_U32(p) ((__attribute__((address_space(3))) unsigned int*)(p))
#define GLB_U32(p) ((const __attribute__((address_space(1))) unsigned int*)(p))

// ---------------- workspace layout (float offsets) ----------------
#define OFF_PAS   0
#define OFF_PAE   (OFF_PAS  + BB*TT*HH)
#define OFF_PATT  (OFF_PAE  + BB*TT*HH)
#define OFF_PPS   (OFF_PATT + BB*TT*HH)
#define OFF_PPE   (OFF_PPS  + BB*TT*HH)
#define OFF_END_A (OFF_PPE  + BB*TT*HH)
#define OFF_AEMB  OFF_PAS
#define OFF_PEMB  OFF_PAE
#define OFF_CPA   OFF_PATT
#define OFF_CPP   OFF_PPS
#define OFF_APROJ OFF_PPE
#define OFF_PPROJ (OFF_PPE + BB*KARG*HH)
#define OFF_LOG   OFF_END_A
#define OFF_WT    (OFF_LOG  + BB*TT)
#define OFF_AIDX  (OFF_WT   + NWc*HH)
#define OFF_PIDX  (OFF_AIDX + BB*KARG)
#define OFF_ASC   (OFF_PIDX + BB*KPRED)
#define OFF_PSC   (OFF_ASC  + BB*KARG)
#define OFF_SPLIT (OFF_PSC + BB*KPRED)
#define XSLAB_U   (4096*1024)
#define WSLAB_U   (5*1024*1024)

// ---------------- d_out layout (float offsets) ----------------
#define O_SRL 0
#define O_TPS (O_SRL + BB*KPRED*KARG*NCLSc)
#define O_TAS (O_TPS + BB*KPRED*2)
#define O_TPM (O_TAS + BB*KARG*2)
#define O_TAM (O_TPM + BB*KPRED)
#define O_PFS (O_TAM + BB*KARG)
#define O_AFS (O_PFS + BB*NPc)

__device__ inline float4 f4_add(const float4&a,const float4&b){return make_float4(a.x+b.x,a.y+b.y,a.z+b.z,a.w+b.w);}
__device__ inline float4 f4_fma(float c,const float4&v,const float4&a){return make_float4(fmaf(c,v.x,a.x),fmaf(c,v.y,a.y),fmaf(c,v.z,a.z),fmaf(c,v.w,a.w));}
__device__ inline float4 f4_scale(const float4&v,float c){return make_float4(v.x*c,v.y*c,v.z*c,v.w*c);}
__device__ inline float4 f4_relu(const float4&v){return make_float4(fmaxf(v.x,0.f),fmaxf(v.y,0.f),fmaxf(v.z,0.f),fmaxf(v.w,0.f));}

// bf16 round-to-nearest-even from fp32 bits
__device__ inline unsigned short bf16r(float f) {
  unsigned int u = __float_as_uint(f);
  u = (u + 0x7FFFu + ((u >> 16) & 1u)) >> 16;
  return (unsigned short)u;
}
__device__ inline float bf2f(unsigned short h) { return __uint_as_float(((unsigned int)h) << 16); }

__device__ inline f32x4 mfma16(bf16x8 a, bf16x8 b, f32x4 c) {
  return __builtin_amdgcn_mfma_f32_16x16x32_bf16(a, b, c, 0, 0, 0);
}

// ---------------- K1: global attention logits ----------------
__global__ __launch_bounds__(256) void k_logits(const float* __restrict__ f, const float* __restrict__ Watt,
    const float* __restrict__ batt, float* __restrict__ lg) {
  const int lane = threadIdx.x & 63, wv = threadIdx.x >> 6;
  const int r = blockIdx.x*4 + wv;
  const float4* x = (const float4*)&f[(size_t)r*HH];
  const float4* wt = (const float4*)Watt;
  float s = 0.f;
  #pragma unroll
  for (int i=0;i<4;++i) {
    const float4 v = x[lane + i*64];
    const float4 w = wt[lane + i*64];
    s += v.x*w.x + v.y*w.y + v.z*w.z + v.w*w.w;
  }
  for (int o=32;o>0;o>>=1) s += __shfl_down(s,o,64);
  if (lane==0) lg[r] = s + batt[0];
}

// ---------------- width table: WT[w] = W_width[w] @ Wa1[2048:2068] (fp32 exact) ----------------
__global__ __launch_bounds__(256) void k_wtab(const float* __restrict__ Wwidth, const float* __restrict__ src,
    float* __restrict__ WT) {
  const int w = blockIdx.x; const int j = threadIdx.x*4;
  float4 acc = make_float4(0,0,0,0);
  for (int d=0; d<WDc; ++d) {
    const float c = Wwidth[w*WDc+d];
    const float4 v = *(const float4*)&src[d*HH + j];
    acc = f4_fma(c, v, acc);
  }
  *(float4*)&WT[w*HH + j] = acc;
}

// ---------------- split X into 3 bf16 slabs (exact decomposition) ----------------
__global__ __launch_bounds__(256) void k_splitX(const float* __restrict__ f,
    unsigned short* __restrict__ X0, unsigned short* __restrict__ X1, unsigned short* __restrict__ X2) {
  const size_t i = ((size_t)blockIdx.x*256 + threadIdx.x) * 4;
  const float4 v = *(const float4*)&f[i];
  float a[4] = {v.x, v.y, v.z, v.w};
  unsigned short r0[4], r1[4], r2[4];
  #pragma unroll
  for (int q=0;q<4;++q) {
    r0[q] = bf16r(a[q]);            float rem1 = a[q] - bf2f(r0[q]);
    r1[q] = bf16r(rem1);            float rem2 = rem1 - bf2f(r1[q]);
    r2[q] = bf16r(rem2);
  }
  *(ushort4*)&X0[i] = make_ushort4(r0[0],r0[1],r0[2],r0[3]);
  *(ushort4*)&X1[i] = make_ushort4(r1[0],r1[1],r1[2],r1[3]);
  *(ushort4*)&X2[i] = make_ushort4(r2[0],r2[1],r2[2],r2[3]);
}

// ---------------- split + transpose W parts: Wt[s][part][n][k] bf16 ----------------
__global__ __launch_bounds__(256) void k_splitW(const float* __restrict__ Wa1, const float* __restrict__ Wp1,
    unsigned short* __restrict__ W0, unsigned short* __restrict__ W1, unsigned short* __restrict__ W2) {
  const int part = blockIdx.z;
  const float* srcs[5] = {Wa1, Wa1 + 1024*1024, Wa1 + 2068*1024, Wp1, Wp1 + 1024*1024};
  const float* __restrict__ src = srcs[part];
  const size_t po = (size_t)part * 1024 * 1024;
  const int k0 = blockIdx.x * 32, n0 = blockIdx.y * 32;
  __shared__ float tile[32][33];
  const int c = threadIdx.x & 31, r0 = threadIdx.x >> 5;   // r0: 0..7
  #pragma unroll
  for (int q=0;q<4;++q) {
    const int row = r0 + 8*q;                               // k-local
    tile[row][c] = src[(size_t)(k0+row)*1024 + n0 + c];
  }
  __syncthreads();
  #pragma unroll
  for (int q=0;q<4;++q) {
    const int nl = r0 + 8*q;                                // n-local
    const float v = tile[c][nl];                            // transposed read
    const unsigned short h0 = bf16r(v);   const float rem1 = v - bf2f(h0);
    const unsigned short h1 = bf16r(rem1); const float rem2 = rem1 - bf2f(h1);
    const unsigned short h2 = bf16r(rem2);
    const size_t oi = po + (size_t)(n0+nl)*1024 + k0 + c;
    W0[oi] = h0; W1[oi] = h1; W2[oi] = h2;
  }
}

// ---------------- K2: 6-term split GEMM as ONE bf16 GEMM with K=6144, XOR-swizzled LDS ----
// Terms t=0..5: (Xa,Wb) = (0,0),(0,1),(1,0),(1,1),(0,2),(2,0).
// LDS tile [128 rows][8 slots of 16B]; element-block e of row r lives at slot e ^ (r&7).
// Rule #21: global_load_lds dest is linear, so the SOURCE address carries the inverse
// permutation (e = (l&7) ^ (l>>3)); ds_read applies the same involution. This breaks the
// 16-way bank conflict of the 128B-stride row-major tile (round-7 PMC: 9.4e7 conflicts).
__global__ __launch_bounds__(256) void k_mgemm(
    const unsigned short* __restrict__ X0, const unsigned short* __restrict__ X1, const unsigned short* __restrict__ X2,
    const unsigned short* __restrict__ W0, const unsigned short* __restrict__ W1, const unsigned short* __restrict__ W2,
    float* __restrict__ proj) {
  const int part = blockIdx.z;
  const int rb = blockIdx.x * 128, cb = blockIdx.y * 128;
  float* __restrict__ C = proj + (size_t)part * (4096*1024);
  const size_t po = (size_t)part * 1024 * 1024;

  __shared__ unsigned short As[128][64];   // 16 KB
  __shared__ unsigned short Bs[128][64];   // 16 KB

  const int tid = threadIdx.x;
  const int lane = tid & 63, wave = tid >> 6;
  const int wr = wave >> 1, wc = wave & 1;          // 2x2 waves, 64x64 each
  const int r16 = lane & 15, g4 = lane >> 4;        // fragment row / k-group

  // staging: wave w, instr i covers rows [w*32+i*8, +8); lane l -> row rl+(l>>3), LDS slot l&7.
  // swizzle: that slot must hold element-block (l&7) ^ (row&7) = (l&7) ^ (l>>3)  [rl % 8 == 0]
  const int srow = (lane >> 3);                 // 0..7
  const int sseg = ((lane & 7) ^ srow) * 8;     // swizzled source element-block (bf16 units)

  f32x4 acc[4][4];
  #pragma unroll
  for (int i=0;i<4;++i)
    #pragma unroll
    for (int j=0;j<4;++j) acc[i][j] = (f32x4){0.f,0.f,0.f,0.f};

  const unsigned short* const XA[6] = {X0, X0, X1, X1, X0, X2};
  const unsigned short* const WB[6] = {W0+po, W1+po, W0+po, W1+po, W2+po, W0+po};

  const int r7 = r16 & 7;   // row&7 for all fragment rows (wr*64, wc*64, mf*16 are mult. of 8)

  #pragma unroll
  for (int t = 0; t < 6; ++t) {
    const unsigned short* __restrict__ ap = XA[t];
    const unsigned short* __restrict__ bp = WB[t];
    for (int kc = 0; kc < 16; ++kc) {
      const int kbase = kc * 64;
      #pragma unroll
      for (int i = 0; i < 4; ++i) {
        const int rl = wave*32 + i*8;
        __builtin_amdgcn_global_load_lds(
            GLB_U32(ap + (size_t)(rb + rl + srow)*1024 + kbase + sseg),
            LDS_U32(&As[rl][0]), 16, 0, 0);
        __builtin_amdgcn_global_load_lds(
            GLB_U32(bp + (size_t)(cb + rl + srow)*1024 + kbase + sseg),
            LDS_U32(&Bs[rl][0]), 16, 0, 0);
      }
      __syncthreads();   // vmcnt(0) drain + barrier

      #pragma unroll
      for (int ks = 0; ks < 2; ++ks) {
        const int col = (((ks*4 + g4) ^ r7)) * 8;   // swizzled read column (bf16 units)
        bf16x8 a[4], b[4];
        #pragma unroll
        for (int mf=0; mf<4; ++mf)
          a[mf] = *reinterpret_cast<const bf16x8*>(&As[wr*64 + mf*16 + r16][col]);
        #pragma unroll
        for (int nf=0; nf<4; ++nf)
          b[nf] = *reinterpret_cast<const bf16x8*>(&Bs[wc*64 + nf*16 + r16][col]);
        #pragma unroll
        for (int mf=0; mf<4; ++mf)
          #pragma unroll
          for (int nf=0; nf<4; ++nf)
            acc[mf][nf] = mfma16(a[mf], b[nf], acc[mf][nf]);
      }
      __syncthreads();
    }
  }

  // C/D layout (m89-verified): col = lane&15, row = (lane>>4)*4 + reg
  const int colb = cb + wc*64 + r16;
  const int rowb = rb + wr*64 + g4 * 4;
  #pragma unroll
  for (int mf=0; mf<4; ++mf)
    #pragma unroll
    for (int nf=0; nf<4; ++nf)
      #pragma unroll
      for (int r=0; r<4; ++r)
        C[(size_t)(rowb + mf*16 + r) * 1024 + colb + nf*16] = acc[mf][nf][r];
}

// ---------------- attention weight helper ----------------
__device__ inline void att_weights(const float* __restrict__ logits, int b, int sr, int er,
                                   float aw[16], int idxs[16]) {
  const int wdt = er - sr;
  float mx = -1e30f;
  #pragma unroll
  for (int w=0; w<16; ++w) {
    const bool valid = (w <= wdt) && (er - w >= 0);
    idxs[w] = max(er - w, 0);
    aw[w] = valid ? logits[b*TT + idxs[w]] : -1e30f;
    mx = fmaxf(mx, aw[w]);
  }
  float ssum = 0.f;
  #pragma unroll
  for (int w=0; w<16; ++w) { aw[w] = expf(aw[w]-mx); ssum += aw[w]; }
  const float inv = 1.f/ssum;
  #pragma unroll
  for (int w=0; w<16; ++w) {
    const bool valid = (w <= wdt) && (er - w >= 0);
    aw[w] = valid ? aw[w]*inv : 0.f;
  }
}

// ---------------- K3: arg prune scores ----------------
__global__ __launch_bounds__(256) void k_argscore(const int* __restrict__ cand,
    const float* __restrict__ logits, const float* __restrict__ Pas, const float* __restrict__ Pae,
    const float* __restrict__ Patt, const float* __restrict__ WT,
    const float* __restrict__ ba1, const float* __restrict__ Wa2, const float* __restrict__ ba2,
    float* __restrict__ osc) {
  const int g = blockIdx.x;       // b*NA + n
  const int b = g >> 10;
  const int t = threadIdx.x;
  const int sr = cand[g*2], er = cand[g*2+1];
  if (er <= 0) { if (t==0) osc[g] = NEGV; return; }
  const int s = sr, e = er;
  const int wc = min(max(e - s, 0), NWc-1);
  float aw[16]; int idxs[16];
  att_weights(logits, b, sr, er, aw, idxs);
  float4 h = ((const float4*)&Pas[(size_t)(b*TT+s)*HH])[t];
  h = f4_add(h, ((const float4*)&Pae[(size_t)(b*TT+e)*HH])[t]);
  h = f4_add(h, ((const float4*)&WT[(size_t)wc*HH])[t]);
  #pragma unroll
  for (int w=0; w<16; ++w) if (aw[w] != 0.f) {
    const float4 v = ((const float4*)&Patt[(size_t)(b*TT+idxs[w])*HH])[t];
    h = f4_fma(aw[w], v, h);
  }
  h = f4_add(h, ((const float4*)ba1)[t]);
  h = f4_relu(h);
  const float4 w2 = ((const float4*)Wa2)[t];
  float part = h.x*w2.x + h.y*w2.y + h.z*w2.z + h.w*w2.w;
  for (int o=32;o>0;o>>=1) part += __shfl_down(part,o,64);
  __shared__ float red[4];
  const int lane = t & 63, wvi = t >> 6;
  if (lane==0) red[wvi] = part;
  __syncthreads();
  if (t==0) osc[g] = red[0]+red[1]+red[2]+red[3] + ba2[0];
}

// ---------------- K4: pred prune scores ----------------
__global__ __launch_bounds__(256) void k_predscore(const int* __restrict__ cand,
    const float* __restrict__ Pps, const float* __restrict__ Ppe,
    const float* __restrict__ bp1, const float* __restrict__ Wp2, const float* __restrict__ bp2,
    float* __restrict__ osc) {
  const int g = blockIdx.x;       // b*NP + n
  const int b = g >> 9;
  const int t = threadIdx.x;
  const int sr = cand[g*2], er = cand[g*2+1];
  if (er <= 0) { if (t==0) osc[g] = NEGV; return; }
  float4 h = ((const float4*)&Pps[(size_t)(b*TT+sr)*HH])[t];
  h = f4_add(h, ((const float4*)&Ppe[(size_t)(b*TT+er)*HH])[t]);
  h = f4_add(h, ((const float4*)bp1)[t]);
  h = f4_relu(h);
  const float4 w2 = ((const float4*)Wp2)[t];
  float part = h.x*w2.x + h.y*w2.y + h.z*w2.z + h.w*w2.w;
  for (int o=32;o>0;o>>=1) part += __shfl_down(part,o,64);
  __shared__ float red[4];
  const int lane = t & 63, wvi = t >> 6;
  if (lane==0) red[wvi] = part;
  __syncthreads();
  if (t==0) osc[g] = red[0]+red[1]+red[2]+red[3] + bp2[0];
}

// ---------------- K5: top-k (lax.top_k semantics) + outputs ----------------
__global__ __launch_bounds__(256) void k_topk(const float* __restrict__ fullsc, const int* __restrict__ cand,
    int N, int K, float frac, float* __restrict__ o_spans, float* __restrict__ o_mask,
    float* __restrict__ o_tsc, int* __restrict__ o_idx) {
  const int b = blockIdx.x;
  const int t = threadIdx.x;
  __shared__ float sv[1024];
  __shared__ int sel[32];
  __shared__ float bv[4]; __shared__ int bi[4];
  __shared__ int mcnt; __shared__ int snk;
  const float* sc = fullsc + (size_t)b*N;
  const int* cd = cand + (size_t)b*N*2;
  if (t==0) mcnt = 0;
  __syncthreads();
  int cnt = 0;
  for (int i=t;i<N;i+=256){ sv[i]=sc[i]; if (cd[i*2+1] > 0) cnt++; }
  atomicAdd(&mcnt, cnt);
  __syncthreads();
  const int lane = t & 63, wvi = t >> 6;
  for (int k=0;k<K;++k) {
    float best = -INFINITY; int bidx = 1<<30;
    for (int i=t;i<N;i+=256){ const float v=sv[i]; if (v>best){best=v;bidx=i;} }
    for (int o=32;o>0;o>>=1){
      const float v2 = __shfl_down(best,o,64); const int i2 = __shfl_down(bidx,o,64);
      if (v2>best || (v2==best && i2<bidx)) {best=v2;bidx=i2;}
    }
    if (lane==0){bv[wvi]=best;bi[wvi]=bidx;}
    __syncthreads();
    if (t==0){
      float bb=bv[0]; int ii=bi[0];
      for (int w=1;w<4;++w){ if (bv[w]>bb || (bv[w]==bb && bi[w]<ii)){bb=bv[w];ii=bi[w];} }
      sel[k]=ii; sv[ii] = -INFINITY;
    }
    __syncthreads();
  }
  if (t==0) {
    int nk = (int)((float)mcnt * frac); if (nk > K) nk = K;
    snk = nk;
    int fill = 0;
    for (int k=0;k<K;++k) fill = max(fill, sel[k]);
    for (int k=nk;k<K;++k) sel[k] = fill;
    for (int k=1;k<K;++k){ int v=sel[k]; int j=k-1; while(j>=0 && sel[j]>v){sel[j+1]=sel[j];--j;} sel[j+1]=v; }
  }
  __syncthreads();
  if (t < K) {
    const int id = sel[t];
    const int s0 = cd[id*2], e0 = cd[id*2+1];
    o_spans[(b*K+t)*2]   = (float)s0;
    o_spans[(b*K+t)*2+1] = (float)e0;
    o_mask[b*K+t] = (t < snk && e0 > 0) ? 1.f : 0.f;
    o_tsc[b*K+t] = sc[id];
    o_idx[b*K+t] = id;
  }
}

// ---------------- K7a/b: build compact embedding rows for kept spans ----------------
__global__ __launch_bounds__(256) void k_build_pemb(const float* __restrict__ f, const int* __restrict__ cand,
    const int* __restrict__ tidx, float* __restrict__ Pemb) {
  const int r = blockIdx.x;           // 0..119
  const int b = r / KPRED;
  const int id = tidx[r];
  int s = cand[(b*NPc+id)*2], e = cand[(b*NPc+id)*2+1];
  const float mf = (e > 0) ? 1.f : 0.f;
  if (e <= 0) { s = 0; e = 0; }
  const int t = threadIdx.x;
  const float4 fs = ((const float4*)&f[(size_t)(b*TT+s)*HH])[t];
  const float4 fe = ((const float4*)&f[(size_t)(b*TT+e)*HH])[t];
  float4* o = (float4*)&Pemb[(size_t)r*2048];
  o[t]     = f4_scale(fs, mf);
  o[256+t] = f4_scale(fe, mf);
}

__global__ __launch_bounds__(256) void k_build_aemb(const float* __restrict__ f, const int* __restrict__ cand,
    const int* __restrict__ tidx, const float* __restrict__ logits, const float* __restrict__ Wwidth,
    float* __restrict__ Aemb) {
  const int r = blockIdx.x;           // 0..239
  const int b = r / KARG;
  const int id = tidx[r];
  const int sr = cand[(b*NAc+id)*2], er = cand[(b*NAc+id)*2+1];
  const float mf = (er > 0) ? 1.f : 0.f;
  const int s = (er > 0) ? sr : 0, e = (er > 0) ? er : 0;
  const int wc = min(max(e - s, 0), NWc-1);
  float aw[16]; int idxs[16];
  att_weights(logits, b, sr, er, aw, idxs);
  const int t = threadIdx.x;
  float* rowp = &Aemb[(size_t)r*3092];
  const float4 fs  = ((const float4*)&f[(size_t)(b*TT+s)*HH])[t];
  const float4 fe4 = ((const float4*)&f[(size_t)(b*TT+e)*HH])[t];
  ((float4*)rowp)[t]        = f4_scale(fs, mf);
  ((float4*)(rowp+1024))[t] = f4_scale(fe4, mf);
  if (t < WDc) rowp[2048+t] = Wwidth[wc*WDc+t]*mf;
  float4 acc = make_float4(0,0,0,0);
  #pragma unroll
  for (int w=0; w<16; ++w) if (aw[w] != 0.f) {
    const float4 fv = ((const float4*)&f[(size_t)(b*TT+idxs[w])*HH])[t];
    acc = f4_fma(aw[w], fv, acc);
  }
  ((float4*)(rowp+2068))[t] = f4_scale(acc, mf);
}

// ---------------- K7c: small-M GEMM with k-split: Cp[kz] = A[b-rows] @ W ----------------
template<int MT>
__global__ __launch_bounds__(256) void k_sgemm(const float* __restrict__ A, int lda, int K,
                                               const float* __restrict__ W, float* __restrict__ Cp) {
  const int ct = blockIdx.x;          // 8 col tiles of 128
  const int b  = blockIdx.y;          // 8 batches
  const int kz = blockIdx.z;          // 4 k splits
  const int Mtotal = 8*MT;
  const int cbase = ct*128;
  const int rbase = b*MT;
  const int klen = K/4;
  const int kbeg = kz*klen, kend = kbeg + klen;
  __shared__ float As[MT][64];
  const int tid = threadIdx.x;
  const int lane = tid & 63, wv = tid >> 6;
  const int ks = lane & 7;
  const int cg = wv*8 + (lane >> 3);  // 0..31
  const int col = cbase + cg*4;
  float acc[MT][4];
  #pragma unroll
  for (int m=0;m<MT;++m){acc[m][0]=0.f;acc[m][1]=0.f;acc[m][2]=0.f;acc[m][3]=0.f;}
  for (int k0 = kbeg; k0 < kend; k0 += 64) {
    const int kc = min(64, kend - k0);
    for (int i = tid; i < MT*64; i += 256) {
      const int m = i >> 6, kk = i & 63;
      As[m][kk] = (kk < kc) ? A[(size_t)(rbase+m)*lda + k0 + kk] : 0.f;
    }
    __syncthreads();
    const int kmax = min(8, kc - ks*8);
    for (int i = 0; i < kmax; ++i) {
      const int kk = ks*8 + i;
      const float4 wv4 = *(const float4*)&W[(size_t)(k0+kk)*1024 + col];
      #pragma unroll
      for (int m=0;m<MT;++m) {
        const float av = As[m][kk];
        acc[m][0] = fmaf(av, wv4.x, acc[m][0]);
        acc[m][1] = fmaf(av, wv4.y, acc[m][1]);
        acc[m][2] = fmaf(av, wv4.z, acc[m][2]);
        acc[m][3] = fmaf(av, wv4.w, acc[m][3]);
      }
    }
    __syncthreads();
  }
  #pragma unroll
  for (int m=0;m<MT;++m) {
    #pragma unroll
    for (int j=0;j<4;++j) {
      float v = acc[m][j];
      v += __shfl_xor(v, 1, 64);
      v += __shfl_xor(v, 2, 64);
      v += __shfl_xor(v, 4, 64);
      acc[m][j] = v;
    }
  }
  if (ks == 0) {
    #pragma unroll
    for (int m=0;m<MT;++m) {
      const float4 v = make_float4(acc[m][0],acc[m][1],acc[m][2],acc[m][3]);
      *(float4*)&Cp[((size_t)kz*Mtotal + rbase + m)*1024 + col] = v;
    }
  }
}

__global__ void k_reduce4(const float* __restrict__ Cp, float* __restrict__ Co, int n) {
  const int i = blockIdx.x*256 + threadIdx.x;
  if (i < n) Co[i] = Cp[i] + Cp[(size_t)n+i] + Cp[2*(size_t)n+i] + Cp[3*(size_t)n+i];
}

// ---------------- K8: pairwise 65-class scorer ----------------
__global__ __launch_bounds__(256) void k_final(const float* __restrict__ pproj, const float* __restrict__ aproj,
    const float* __restrict__ bs1, const float* __restrict__ Ws2, const float* __restrict__ bs2,
    const float* __restrict__ tasc, const float* __restrict__ tpsc, float* __restrict__ srl) {
  const int g = blockIdx.x;           // b*450 + p*30 + a
  const int b = g / (KPRED*KARG);
  const int rem = g % (KPRED*KARG);
  const int p = rem / KARG, a = rem % KARG;
  const int t = threadIdx.x;
  __shared__ float h[1024];
  __shared__ float part[4][64];
  __shared__ float r64[4];
  {
    const float4 pv = ((const float4*)&pproj[(size_t)(b*KPRED+p)*HH])[t];
    const float4 av = ((const float4*)&aproj[(size_t)(b*KARG+a)*HH])[t];
    const float4 bv = ((const float4*)bs1)[t];
    float4 v;
    v.x = fmaxf(pv.x+av.x+bv.x, 0.f);
    v.y = fmaxf(pv.y+av.y+bv.y, 0.f);
    v.z = fmaxf(pv.z+av.z+bv.z, 0.f);
    v.w = fmaxf(pv.w+av.w+bv.w, 0.f);
    ((float4*)h)[t] = v;
  }
  __syncthreads();
  const int j = t & 63, sl = t >> 6;
  float accj = 0.f, acc64 = 0.f;
  const int kb = sl*256;
  for (int kk = kb; kk < kb+256; ++kk) {
    const float hv = h[kk];
    accj = fmaf(hv, Ws2[(size_t)kk*65 + j], accj);
    if (j == 0) acc64 = fmaf(hv, Ws2[(size_t)kk*65 + 64], acc64);
  }
  part[sl][j] = accj;
  if (j == 0) r64[sl] = acc64;
  __syncthreads();
  const float base = tasc[b*KARG+a] + tpsc[b*KPRED+p];
  float* o = &srl[(size_t)g*NCLSc];
  if (t < 64) {
    o[1+t] = part[0][t]+part[1][t]+part[2][t]+part[3][t] + bs2[t] + base;
  } else if (t == 64) {
    o[0] = 0.f;
    o[65] = r64[0]+r64[1]+r64[2]+r64[3] + bs2[64] + base;
  }
}

// ---------------- launch ----------------
extern "C" void kernel_launch(void* const* d_in, const int* in_sizes, int n_in,
                              void* d_out, int out_size, void* d_ws, size_t ws_size,
                              hipStream_t stream) {
  const float* features = (const float*)d_in[0];
  const int*   argc_    = (const int*)d_in[1];
  const int*   predc    = (const int*)d_in[2];
  const float* Wwidth   = (const float*)d_in[3];
  const float* Watt     = (const float*)d_in[4];
  const float* batt     = (const float*)d_in[5];
  const float* Wa1      = (const float*)d_in[6];
  const float* ba1      = (const float*)d_in[7];
  const float* Wa2      = (const float*)d_in[8];
  const float* ba2      = (const float*)d_in[9];
  const float* Wp1      = (const float*)d_in[10];
  const float* bp1      = (const float*)d_in[11];
  const float* Wp2      = (const float*)d_in[12];
  const float* bp2      = (const float*)d_in[13];
  const float* Ws1      = (const float*)d_in[14];
  const float* bs1      = (const float*)d_in[15];
  const float* Ws2      = (const float*)d_in[16];
  const float* bs2      = (const float*)d_in[17];
  float* ws  = (float*)d_ws;
  float* out = (float*)d_out;

  unsigned short* X0 = (unsigned short*)(ws + OFF_SPLIT);
  unsigned short* X1 = X0 + XSLAB_U;
  unsigned short* X2 = X1 + XSLAB_U;
  unsigned short* W0 = X2 + XSLAB_U;
  unsigned short* W1 = W0 + WSLAB_U;
  unsigned short* W2 = W1 + WSLAB_U;

  // 1. logits
  k_logits<<<dim3(BB*TT/4), 256, 0, stream>>>(features, Watt, batt, ws + OFF_LOG);
  // 2. width table (fp32 exact)
  k_wtab<<<dim3(NWc), 256, 0, stream>>>(Wwidth, Wa1 + 2048*1024, ws + OFF_WT);
  // 3. split X and the 5 W parts into 3-way bf16 (W transposed to [n][k])
  k_splitX<<<dim3(4096), 256, 0, stream>>>(features, X0, X1, X2);
  k_splitW<<<dim3(32, 32, 5), 256, 0, stream>>>(Wa1, Wp1, W0, W1, W2);
  // 4. MFMA GEMM, K=6144 slab-pair schedule, XOR-swizzled LDS
  k_mgemm<<<dim3(32, 8, 5), 256, 0, stream>>>(X0, X1, X2, W0, W1, W2, ws + OFF_PAS);
  // 5. prune scores (consume projections; Region A dead afterwards)
  k_argscore<<<dim3(BB*NAc), 256, 0, stream>>>(argc_, ws + OFF_LOG, ws + OFF_PAS, ws + OFF_PAE,
      ws + OFF_PATT, ws + OFF_WT, ba1, Wa2, ba2, out + O_AFS);
  k_predscore<<<dim3(BB*NPc), 256, 0, stream>>>(predc, ws + OFF_PPS, ws + OFF_PPE,
      bp1, Wp2, bp2, out + O_PFS);
  // 6. top-k + span/mask outputs
  k_topk<<<dim3(BB), 256, 0, stream>>>(out + O_AFS, argc_, NAc, KARG, 0.8f,
      out + O_TAS, out + O_TAM, ws + OFF_ASC, (int*)(ws + OFF_AIDX));
  k_topk<<<dim3(BB), 256, 0, stream>>>(out + O_PFS, predc, NPc, KPRED, 0.4f,
      out + O_TPS, out + O_TPM, ws + OFF_PSC, (int*)(ws + OFF_PIDX));
  // 7. build compact embeddings for kept spans (aliased over Region A — stream-ordered, safe)
  k_build_aemb<<<dim3(BB*KARG), 256, 0, stream>>>(features, argc_, (const int*)(ws + OFF_AIDX),
      ws + OFF_LOG, Wwidth, ws + OFF_AEMB);
  k_build_pemb<<<dim3(BB*KPRED), 256, 0, stream>>>(features, predc, (const int*)(ws + OFF_PIDX),
      ws + OFF_PEMB);
  // 8. pairwise projections (fp32 small GEMMs, k-split x4) + reduce
  k_sgemm<KARG><<<dim3(8, 8, 4), 256, 0, stream>>>(ws + OFF_AEMB, 3092, 3092, Ws1 + (size_t)2048*1024, ws + OFF_CPA);
  k_sgemm<KPRED><<<dim3(8, 8, 4), 256, 0, stream>>>(ws + OFF_PEMB, 2048, 2048, Ws1, ws + OFF_CPP);
  k_reduce4<<<dim3((BB*KARG*HH + 255)/256), 256, 0, stream>>>(ws + OFF_CPA, ws + OFF_APROJ, BB*KARG*HH);
  k_reduce4<<<dim3((BB*KPRED*HH + 255)/256), 256, 0, stream>>>(ws + OFF_CPP, ws + OFF_PPROJ, BB*KPRED*HH);
  // 9. pairwise scorer -> srl_scores
  k_final<<<dim3(BB*KPRED*KARG), 256, 0, stream>>>(ws + OFF_PPROJ, ws + OFF_APROJ,
      bs1, Ws2, bs2, ws + OFF_ASC, ws + OFF_PSC, out + O_SRL);
}